// Round 2
// baseline (33931.378 us; speedup 1.0000x reference)
//
#include <hip/hip_runtime.h>
#include <math.h>

// Problem constants
#define B 256
#define Hh 512
#define S 200
#define T 200
#define VOC 512
#define G3 1536
#define PAD 36

// fp64 helpers: all inner-product math is done in double ("truth-centered"),
// all tensor-boundary values are quantized to fp32 like the reference.
struct d4 { double x, y, z, w; };
__device__ __forceinline__ d4 tod4(const float4 a) {
    d4 r; r.x = a.x; r.y = a.y; r.z = a.z; r.w = a.w; return r;
}
__device__ __forceinline__ double dotd(const d4& a, const d4& b) {
    return a.x * b.x + a.y * b.y + a.z * b.z + a.w * b.w;
}
__device__ __forceinline__ double sigd(double x) { return 1.0 / (1.0 + exp(-x)); }

// ---------------------------------------------------------------------------
// Generic tiled GEMM (fp64 accum): C[m,j] = act( sum_k A[m,k]*W[j*ldw+woff+k]
//                                   + bias[j] + tab[tok(m)*512 + j] )
// M = gridDim.y*32, N = gridDim.x*32, K = 512. act: 0 none, 1 relu, 2 tanh
// ---------------------------------------------------------------------------
__global__ __launch_bounds__(256) void gemm_at(
    const float* __restrict__ A,
    const float* __restrict__ W, int ldw, int woff,
    const float* __restrict__ bias,
    const float* __restrict__ tab, const int* __restrict__ tseq, int t,
    float* __restrict__ C, int ldc, int act)
{
    __shared__ float As[32][PAD];
    __shared__ float Ws[32][PAD];
    const int tid = threadIdx.x;
    const int tx = tid & 15, ty = tid >> 4;
    const int j0 = blockIdx.x * 32, m0 = blockIdx.y * 32;
    const int lr = tid >> 3, lc = (tid & 7) * 4;

    double acc00 = 0.0, acc01 = 0.0, acc10 = 0.0, acc11 = 0.0;

    for (int k0 = 0; k0 < 512; k0 += 32) {
        float4 av = *(const float4*)(A + (size_t)(m0 + lr) * 512 + k0 + lc);
        float4 wv = *(const float4*)(W + (size_t)(j0 + lr) * ldw + woff + k0 + lc);
        __syncthreads();
        *(float4*)&As[lr][lc] = av;
        *(float4*)&Ws[lr][lc] = wv;
        __syncthreads();
#pragma unroll
        for (int kk = 0; kk < 32; kk += 4) {
            d4 a0 = tod4(*(const float4*)&As[ty][kk]);
            d4 a1 = tod4(*(const float4*)&As[ty + 16][kk]);
            d4 b0 = tod4(*(const float4*)&Ws[tx][kk]);
            d4 b1 = tod4(*(const float4*)&Ws[tx + 16][kk]);
            acc00 += dotd(a0, b0);
            acc01 += dotd(a0, b1);
            acc10 += dotd(a1, b0);
            acc11 += dotd(a1, b1);
        }
    }

    const int ms[2] = { m0 + ty, m0 + ty + 16 };
    const int js[2] = { j0 + tx, j0 + tx + 16 };
    double accs[2][2] = { { acc00, acc01 }, { acc10, acc11 } };
#pragma unroll
    for (int mi = 0; mi < 2; ++mi) {
#pragma unroll
        for (int ji = 0; ji < 2; ++ji) {
            int m = ms[mi], j = js[ji];
            double v = accs[mi][ji];
            if (bias) v += (double)bias[j];
            if (tab) {
                int tok = (t == 0) ? 1 : tseq[(t - 1) * B + m];
                v += (double)tab[(size_t)tok * 512 + j];
            }
            if (act == 1) v = v > 0.0 ? v : 0.0;
            else if (act == 2) v = tanh(v);
            C[(size_t)m * ldc + j] = (float)v;
        }
    }
}

// ---------------------------------------------------------------------------
// Fused encoder GRU step (fp64 accum/gates): gh = h @ Whh.T, gi from table,
// gates, masked h update, enc_out write. Tile: 32 b x 16 j. Grid (32, 8).
// ---------------------------------------------------------------------------
__global__ __launch_bounds__(256) void enc_step(
    const float* __restrict__ h_in, float* __restrict__ h_out,
    const float* __restrict__ gi_tab, const int* __restrict__ iseq,
    const int* __restrict__ ilen, const float* __restrict__ Whh,
    const float* __restrict__ bhh, int s, float* __restrict__ enc_out)
{
    __shared__ float Hs[32][PAD];
    __shared__ float Ws[48][PAD];
    const int tid = threadIdx.x;
    const int tx = tid & 15, ty = tid >> 4;
    const int j0 = blockIdx.x * 16, b0 = blockIdx.y * 32;
    const int lr = tid >> 3, lc = (tid & 7) * 4;

    double ar0 = 0.0, az0 = 0.0, an0 = 0.0;
    double ar1 = 0.0, az1 = 0.0, an1 = 0.0;

    for (int k0 = 0; k0 < 512; k0 += 32) {
        float4 hv = *(const float4*)(h_in + (size_t)(b0 + lr) * 512 + k0 + lc);
        int g0 = lr >> 4, jj0 = lr & 15;
        float4 wv0 = *(const float4*)(Whh + (size_t)(g0 * 512 + j0 + jj0) * 512 + k0 + lc);
        float4 wv1;
        if (tid < 128) {
            int jj1 = lr & 15;
            wv1 = *(const float4*)(Whh + (size_t)(2 * 512 + j0 + jj1) * 512 + k0 + lc);
        }
        __syncthreads();
        *(float4*)&Hs[lr][lc] = hv;
        *(float4*)&Ws[lr][lc] = wv0;
        if (tid < 128) *(float4*)&Ws[32 + lr][lc] = wv1;
        __syncthreads();
#pragma unroll
        for (int kk = 0; kk < 32; kk += 4) {
            d4 a0 = tod4(*(const float4*)&Hs[ty][kk]);
            d4 a1 = tod4(*(const float4*)&Hs[ty + 16][kk]);
            d4 wr = tod4(*(const float4*)&Ws[tx][kk]);
            d4 wz = tod4(*(const float4*)&Ws[16 + tx][kk]);
            d4 wn = tod4(*(const float4*)&Ws[32 + tx][kk]);
            ar0 += dotd(a0, wr); az0 += dotd(a0, wz); an0 += dotd(a0, wn);
            ar1 += dotd(a1, wr); az1 += dotd(a1, wz); an1 += dotd(a1, wn);
        }
    }

    const int j = j0 + tx;
    const double br = (double)bhh[j], bz = (double)bhh[512 + j], bn = (double)bhh[1024 + j];
    double gr[2] = { ar0, ar1 }, gz[2] = { az0, az1 }, gn[2] = { an0, an1 };
#pragma unroll
    for (int bb = 0; bb < 2; ++bb) {
        int b = b0 + ty + 16 * bb;
        int tok = iseq[s * B + b];
        const float* gi = gi_tab + (size_t)tok * G3;
        double r = sigd((double)gi[j] + gr[bb] + br);
        double z = sigd((double)gi[512 + j] + gz[bb] + bz);
        double n = tanh((double)gi[1024 + j] + r * (gn[bb] + bn));
        float hold = h_in[(size_t)b * 512 + j];
        float hn = (float)((1.0 - z) * n + z * (double)hold);
        bool msk = s < ilen[b];
        float hnew = msk ? hn : hold;
        h_out[(size_t)b * 512 + j] = hnew;
        enc_out[((size_t)s * B + b) * 512 + j] = msk ? hnew : 0.f;
    }
}

// ---------------------------------------------------------------------------
// Fused decoder GRU step (fp64): gi = x @ Wih.T + bih, gh = h @ Whh.T + bhh.
// Tile: 32 b x 16 j. Grid (32, 8).
// ---------------------------------------------------------------------------
__global__ __launch_bounds__(256) void dec_gru(
    const float* __restrict__ x, const float* __restrict__ h_in,
    const float* __restrict__ Wih, const float* __restrict__ Whh,
    const float* __restrict__ bih, const float* __restrict__ bhh,
    float* __restrict__ h_out)
{
    __shared__ float Xs[32][PAD];
    __shared__ float Hs[32][PAD];
    __shared__ float Wi[48][PAD];
    __shared__ float Wh[48][PAD];
    const int tid = threadIdx.x;
    const int tx = tid & 15, ty = tid >> 4;
    const int j0 = blockIdx.x * 16, b0 = blockIdx.y * 32;
    const int lr = tid >> 3, lc = (tid & 7) * 4;

    double air0 = 0, aiz0 = 0, ain0 = 0, ahr0 = 0, ahz0 = 0, ahn0 = 0;
    double air1 = 0, aiz1 = 0, ain1 = 0, ahr1 = 0, ahz1 = 0, ahn1 = 0;

    for (int k0 = 0; k0 < 512; k0 += 32) {
        float4 xv = *(const float4*)(x + (size_t)(b0 + lr) * 512 + k0 + lc);
        float4 hv = *(const float4*)(h_in + (size_t)(b0 + lr) * 512 + k0 + lc);
        int g0 = lr >> 4, jj0 = lr & 15;
        float4 wi0 = *(const float4*)(Wih + (size_t)(g0 * 512 + j0 + jj0) * 512 + k0 + lc);
        float4 wh0 = *(const float4*)(Whh + (size_t)(g0 * 512 + j0 + jj0) * 512 + k0 + lc);
        float4 wi1, wh1;
        if (tid < 128) {
            int jj1 = lr & 15;
            wi1 = *(const float4*)(Wih + (size_t)(2 * 512 + j0 + jj1) * 512 + k0 + lc);
            wh1 = *(const float4*)(Whh + (size_t)(2 * 512 + j0 + jj1) * 512 + k0 + lc);
        }
        __syncthreads();
        *(float4*)&Xs[lr][lc] = xv;
        *(float4*)&Hs[lr][lc] = hv;
        *(float4*)&Wi[lr][lc] = wi0;
        *(float4*)&Wh[lr][lc] = wh0;
        if (tid < 128) { *(float4*)&Wi[32 + lr][lc] = wi1; *(float4*)&Wh[32 + lr][lc] = wh1; }
        __syncthreads();
#pragma unroll
        for (int kk = 0; kk < 32; kk += 4) {
            d4 x0 = tod4(*(const float4*)&Xs[ty][kk]);
            d4 x1 = tod4(*(const float4*)&Xs[ty + 16][kk]);
            d4 h0 = tod4(*(const float4*)&Hs[ty][kk]);
            d4 h1 = tod4(*(const float4*)&Hs[ty + 16][kk]);
            d4 wir = tod4(*(const float4*)&Wi[tx][kk]);
            d4 wiz = tod4(*(const float4*)&Wi[16 + tx][kk]);
            d4 win = tod4(*(const float4*)&Wi[32 + tx][kk]);
            d4 whr = tod4(*(const float4*)&Wh[tx][kk]);
            d4 whz = tod4(*(const float4*)&Wh[16 + tx][kk]);
            d4 whn = tod4(*(const float4*)&Wh[32 + tx][kk]);
            air0 += dotd(x0, wir); aiz0 += dotd(x0, wiz); ain0 += dotd(x0, win);
            ahr0 += dotd(h0, whr); ahz0 += dotd(h0, whz); ahn0 += dotd(h0, whn);
            air1 += dotd(x1, wir); aiz1 += dotd(x1, wiz); ain1 += dotd(x1, win);
            ahr1 += dotd(h1, whr); ahz1 += dotd(h1, whz); ahn1 += dotd(h1, whn);
        }
    }

    const int j = j0 + tx;
    const double bir = (double)bih[j], biz = (double)bih[512 + j], bin = (double)bih[1024 + j];
    const double bhr = (double)bhh[j], bhz = (double)bhh[512 + j], bhn = (double)bhh[1024 + j];
    double ir[2] = { air0, air1 }, iz[2] = { aiz0, aiz1 }, in_[2] = { ain0, ain1 };
    double hr[2] = { ahr0, ahr1 }, hz[2] = { ahz0, ahz1 }, hn_[2] = { ahn0, ahn1 };
#pragma unroll
    for (int bb = 0; bb < 2; ++bb) {
        int b = b0 + ty + 16 * bb;
        double r = sigd(ir[bb] + bir + hr[bb] + bhr);
        double z = sigd(iz[bb] + biz + hz[bb] + bhz);
        double n = tanh(in_[bb] + bin + r * (hn_[bb] + bhn));
        float hold = h_in[(size_t)b * 512 + j];
        h_out[(size_t)b * 512 + j] = (float)((1.0 - z) * n + z * (double)hold);
    }
}

// ---------------------------------------------------------------------------
// Flash-style attention (fp64 online softmax): one block per batch element.
// ---------------------------------------------------------------------------
__global__ __launch_bounds__(256) void attn_step(
    const float* __restrict__ enc_out, const float* __restrict__ ah,
    float* __restrict__ ctx)
{
    const int b = blockIdx.x;
    const int tid = threadIdx.x;
    const int wave = tid >> 6, lane = tid & 63;

    const d4 a1 = tod4(*(const float4*)(ah + (size_t)b * 512 + lane * 4));
    const d4 a2 = tod4(*(const float4*)(ah + (size_t)b * 512 + 256 + lane * 4));

    double m = -INFINITY, l = 0.0;
    d4 c1 = { 0, 0, 0, 0 }, c2 = { 0, 0, 0, 0 };

    for (int s = wave; s < S; s += 4) {
        const float* row = enc_out + ((size_t)s * B + b) * 512;
        d4 e1 = tod4(*(const float4*)(row + lane * 4));
        d4 e2 = tod4(*(const float4*)(row + 256 + lane * 4));
        double p = dotd(e1, a1) + dotd(e2, a2);
#pragma unroll
        for (int off = 32; off >= 1; off >>= 1) p += __shfl_xor(p, off, 64);
        double mn = fmax(m, p);
        double sc = exp(m - mn);
        double w = exp(p - mn);
        l = l * sc + w;
        c1.x = c1.x * sc + w * e1.x; c1.y = c1.y * sc + w * e1.y;
        c1.z = c1.z * sc + w * e1.z; c1.w = c1.w * sc + w * e1.w;
        c2.x = c2.x * sc + w * e2.x; c2.y = c2.y * sc + w * e2.y;
        c2.z = c2.z * sc + w * e2.z; c2.w = c2.w * sc + w * e2.w;
        m = mn;
    }

    __shared__ double sm[4], sl[4];
    __shared__ double scx[4][512];
    if (lane == 0) { sm[wave] = m; sl[wave] = l; }
    scx[wave][lane * 4 + 0] = c1.x; scx[wave][lane * 4 + 1] = c1.y;
    scx[wave][lane * 4 + 2] = c1.z; scx[wave][lane * 4 + 3] = c1.w;
    scx[wave][256 + lane * 4 + 0] = c2.x; scx[wave][256 + lane * 4 + 1] = c2.y;
    scx[wave][256 + lane * 4 + 2] = c2.z; scx[wave][256 + lane * 4 + 3] = c2.w;
    __syncthreads();

    double M = fmax(fmax(sm[0], sm[1]), fmax(sm[2], sm[3]));
    double w0 = exp(sm[0] - M), w1 = exp(sm[1] - M);
    double w2 = exp(sm[2] - M), w3 = exp(sm[3] - M);
    double L = sl[0] * w0 + sl[1] * w1 + sl[2] * w2 + sl[3] * w3;

    for (int j = tid; j < 512; j += 256) {
        double v = scx[0][j] * w0 + scx[1][j] * w1 + scx[2][j] * w2 + scx[3][j] * w3;
        ctx[(size_t)b * 512 + j] = (float)(v / L);
    }
}

// ---------------------------------------------------------------------------
// Per-(t,b) softmax over V=512 logits. Probabilities computed in fp64, cast
// to fp32, argmax over fp32 probs with first-index ties (mimics reference
// argmax-over-dists semantics). One block per b.
// ---------------------------------------------------------------------------
__global__ __launch_bounds__(256) void softmax_loss(
    const float* __restrict__ logits, const int* __restrict__ target,
    int t, float* __restrict__ nll, float* __restrict__ inference)
{
    const int b = blockIdx.x, tid = threadIdx.x;
    const float l0 = logits[(size_t)b * 512 + tid];
    const float l1 = logits[(size_t)b * 512 + 256 + tid];

    // fp32 max (exact)
    __shared__ float sv[256];
    sv[tid] = fmaxf(l0, l1);
    __syncthreads();
    for (int off = 128; off > 0; off >>= 1) {
        if (tid < off) sv[tid] = fmaxf(sv[tid], sv[tid + off]);
        __syncthreads();
    }
    const double mx = (double)sv[0];
    __syncthreads();

    // fp64 partition sum
    __shared__ double sd[256];
    const double e0 = exp((double)l0 - mx);
    const double e1 = exp((double)l1 - mx);
    sd[tid] = e0 + e1;
    __syncthreads();
    for (int off = 128; off > 0; off >>= 1) {
        if (tid < off) sd[tid] += sd[tid + off];
        __syncthreads();
    }
    const double Z = sd[0];
    __syncthreads();

    // fp32-quantized probabilities, argmax with first-index tie-break
    const float p0 = (float)(e0 / Z);
    const float p1 = (float)(e1 / Z);
    float v; int idx;
    if (p0 >= p1) { v = p0; idx = tid; } else { v = p1; idx = 256 + tid; }

    __shared__ float pv[256];
    __shared__ int pi[256];
    pv[tid] = v; pi[tid] = idx;
    __syncthreads();
    for (int off = 128; off > 0; off >>= 1) {
        if (tid < off) {
            float ov = pv[tid + off]; int oi = pi[tid + off];
            if (ov > pv[tid] || (ov == pv[tid] && oi < pi[tid])) { pv[tid] = ov; pi[tid] = oi; }
        }
        __syncthreads();
    }

    if (tid == 0) {
        int tgt = target[t * B + b];
        float pt = (float)(exp((double)logits[(size_t)b * 512 + tgt] - mx) / Z);
        pt = fmaxf(pt, 1e-10f);
        nll[t * B + b] = (float)(-log((double)pt));
        inference[t * B + b] = (float)pi[0];
    }
}

// ---------------------------------------------------------------------------
// Final reduction (fp64 sums): loss, acc, all_acc.
// ---------------------------------------------------------------------------
__global__ __launch_bounds__(256) void finalize_k(
    const float* __restrict__ nll, const float* __restrict__ inference,
    const int* __restrict__ target, float* __restrict__ out3)
{
    const int tid = threadIdx.x;
    int wrong = 0;
    double match = 0.0;
    const int b = tid;  // B == 256 == blockDim
    for (int t = 0; t < T; ++t) {
        float inf = inference[t * B + b];
        float tg = (float)target[t * B + b];
        bool ok = (inf == tg);
        match += ok ? 1.0 : 0.0;
        wrong |= !ok;
    }
    double lsum = 0.0;
    for (int i = tid; i < T * B; i += 256) lsum += (double)nll[i];

    __shared__ double sl[256], sm_[256], sa[256];
    sl[tid] = lsum; sm_[tid] = match; sa[tid] = wrong ? 0.0 : 1.0;
    __syncthreads();
    for (int off = 128; off > 0; off >>= 1) {
        if (tid < off) {
            sl[tid] += sl[tid + off];
            sm_[tid] += sm_[tid + off];
            sa[tid] += sa[tid + off];
        }
        __syncthreads();
    }
    if (tid == 0) {
        out3[0] = (float)(sl[0] / (double)(T * B));   // loss
        out3[1] = (float)(sa[0] / (double)B);         // acc
        out3[2] = (float)(sm_[0] / (double)(T * B));  // all_acc
    }
}

// ---------------------------------------------------------------------------
extern "C" void kernel_launch(void* const* d_in, const int* in_sizes, int n_in,
                              void* d_out, int out_size, void* d_ws, size_t ws_size,
                              hipStream_t stream)
{
    const int*   input_seq  = (const int*)d_in[0];    // (S,B)
    const int*   input_len  = (const int*)d_in[1];    // (B,)
    const int*   target_seq = (const int*)d_in[2];    // (T,B)
    const float* enc_embed  = (const float*)d_in[3];  // (V,H)
    const float* enc_Wih    = (const float*)d_in[4];  // (3H,H)
    const float* enc_Whh    = (const float*)d_in[5];  // (3H,H)
    const float* enc_bih    = (const float*)d_in[6];  // (3H,)
    const float* enc_bhh    = (const float*)d_in[7];  // (3H,)
    const float* att_W      = (const float*)d_in[8];  // (H,H)
    const float* att_b      = (const float*)d_in[9];  // (H,)
    const float* dec_embed  = (const float*)d_in[10]; // (V,H)
    const float* dec_Wih    = (const float*)d_in[11]; // (3H,H)
    const float* dec_Whh    = (const float*)d_in[12]; // (3H,H)
    const float* dec_bih    = (const float*)d_in[13]; // (3H,)
    const float* dec_bhh    = (const float*)d_in[14]; // (3H,)
    const float* mlp_W      = (const float*)d_in[15]; // (H,2H)
    const float* mlp_b      = (const float*)d_in[16]; // (H,)
    const float* out_W      = (const float*)d_in[17]; // (V,H)
    const float* out_b      = (const float*)d_in[18]; // (V,)

    float* out = (float*)d_out;  // [inference (T*B) | loss | acc | all_acc]

    float* gi_tab  = (float*)d_ws;                   // (V, 3H)
    float* mlp_tab = gi_tab + (size_t)VOC * G3;      // (V, H)
    float* h_ping  = mlp_tab + (size_t)VOC * Hh;     // (B, H)
    float* h_pong  = h_ping + (size_t)B * Hh;
    float* ah      = h_pong + (size_t)B * Hh;
    float* ctx     = ah + (size_t)B * Hh;
    float* xbuf    = ctx + (size_t)B * Hh;
    float* logits  = xbuf + (size_t)B * Hh;
    float* nll     = logits + (size_t)B * Hh;        // (T, B)
    float* enc_out = nll + (size_t)T * B;            // (S, B, H) ~100 MB

    // h0 = 0
    hipMemsetAsync(h_ping, 0, (size_t)B * Hh * sizeof(float), stream);

    // Precompute: gi_tab[v] = enc_embed[v] @ enc_Wih.T + enc_bih  (512x1536)
    gemm_at<<<dim3(48, 16), 256, 0, stream>>>(
        enc_embed, enc_Wih, 512, 0, enc_bih, nullptr, nullptr, 0, gi_tab, G3, 0);
    // mlp_tab[v] = dec_embed[v] @ mlp_W[:, :512].T + mlp_b  (512x512)
    gemm_at<<<dim3(16, 16), 256, 0, stream>>>(
        dec_embed, mlp_W, 1024, 0, mlp_b, nullptr, nullptr, 0, mlp_tab, Hh, 0);

    // Encoder scan
    for (int s = 0; s < S; ++s) {
        const float* hc = (s & 1) ? h_pong : h_ping;
        float* hx = (s & 1) ? h_ping : h_pong;
        enc_step<<<dim3(32, 8), 256, 0, stream>>>(
            hc, hx, gi_tab, input_seq, input_len, enc_Whh, enc_bhh, s, enc_out);
    }
    // After s=199 (odd) final h is in h_ping.

    // Decoder scan
    for (int t = 0; t < T; ++t) {
        const float* hc = (t & 1) ? h_pong : h_ping;
        float* hx = (t & 1) ? h_ping : h_pong;
        gemm_at<<<dim3(16, 8), 256, 0, stream>>>(
            hc, att_W, 512, 0, att_b, nullptr, nullptr, 0, ah, Hh, 1);
        attn_step<<<dim3(B), 256, 0, stream>>>(enc_out, ah, ctx);
        gemm_at<<<dim3(16, 8), 256, 0, stream>>>(
            ctx, mlp_W, 1024, 512, nullptr, mlp_tab, target_seq, t, xbuf, Hh, 2);
        dec_gru<<<dim3(32, 8), 256, 0, stream>>>(
            xbuf, hc, dec_Wih, dec_Whh, dec_bih, dec_bhh, hx);
        gemm_at<<<dim3(16, 8), 256, 0, stream>>>(
            hx, out_W, 512, 0, out_b, nullptr, nullptr, 0, logits, Hh, 0);
        softmax_loss<<<dim3(B), 256, 0, stream>>>(logits, target_seq, t, nll, out);
    }

    finalize_k<<<dim3(1), 256, 0, stream>>>(nll, out, target_seq, out + (size_t)T * B);
}